// Round 10
// baseline (103.251 us; speedup 1.0000x reference)
//
#include <hip/hip_runtime.h>
#include <hip/hip_bf16.h>
#include <math.h>

#define SD 9216   // S = H*W
#define HH 96     // H = W
#define CC 256    // C
#define NO 768    // 3*C
#define NH 8      // heads
#define DH 32     // head dim
#define NW1 (NO * CC)
#define NWT (NW1 + CC * CC)
#define PROW 232  // padded LDS row (shorts) for Vt

typedef short bf16x8 __attribute__((ext_vector_type(8)));
typedef float f32x4 __attribute__((ext_vector_type(4)));
typedef unsigned short us8 __attribute__((ext_vector_type(8)));

__device__ __forceinline__ unsigned short f2bf(float f) {
  unsigned u = __float_as_uint(f);
  unsigned r = (u + 0x7FFF + ((u >> 16) & 1)) >> 16;  // RNE
  return (unsigned short)r;
}
// async global->LDS, 16B per lane; LDS dest is wave-uniform base + lane*16
__device__ __forceinline__ void gll16(const unsigned short* g, short* l) {
  __builtin_amdgcn_global_load_lds(
      (const __attribute__((address_space(1))) void*)g,
      (__attribute__((address_space(3))) void*)l, 16, 0, 0);
}

// ---- prep: transpose x [C][S] f32 -> xbt [S][C] bf16  AND  convert weights
__global__ __launch_bounds__(256) void prep(const float* __restrict__ x,
                                            const float* __restrict__ wq,
                                            const float* __restrict__ wo,
                                            unsigned short* __restrict__ xbt,
                                            unsigned short* __restrict__ wdst) {
  __shared__ float tile[32][33];
  const int b = blockIdx.x;
  const int t = threadIdx.x;
  if (b < 2304) {
    const int s0 = (b % 288) * 32;
    const int c0 = (b / 288) * 32;
    {
      const int c = t >> 3, s4 = (t & 7) * 4;
      const float4 v = *(const float4*)(x + (size_t)(c0 + c) * SD + s0 + s4);
      tile[c][s4] = v.x; tile[c][s4 + 1] = v.y; tile[c][s4 + 2] = v.z; tile[c][s4 + 3] = v.w;
    }
    __syncthreads();
    {
      const int s = t >> 3, c4 = (t & 7) * 4;
      ushort4 o;
      o.x = f2bf(tile[c4][s]);     o.y = f2bf(tile[c4 + 1][s]);
      o.z = f2bf(tile[c4 + 2][s]); o.w = f2bf(tile[c4 + 3][s]);
      *(ushort4*)(xbt + (size_t)(s0 + s) * CC + c0 + c4) = o;
    }
  } else {
    const int i = ((b - 2304) * 256 + t) * 4;
    if (i < NWT) {
      const float* src = (i < NW1) ? (wq + i) : (wo + (i - NW1));
      const float4 v = *(const float4*)src;
      ushort4 o;
      o.x = f2bf(v.x); o.y = f2bf(v.y); o.z = f2bf(v.z); o.w = f2bf(v.w);
      *(ushort4*)(wdst + i) = o;
    }
  }
}

// ---- bf16 MFMA GEMM, BMxBN tile, BK=64, 4 waves, K = CC = 256.
// global_load_lds staging, XOR chunk swizzle (both-sides). LDS-bounce epilogue:
// EPI 0: D[s][o] bf16 stride NO (qkv proj); EPI 1: D[o][s] f32 stride SD (out proj)
template <int BM, int BN, int EPI>
__global__ __launch_bounds__(256) void gemm_gll(const unsigned short* __restrict__ A,
                                                const unsigned short* __restrict__ Bm,
                                                const float* __restrict__ bias,
                                                void* __restrict__ out) {
  constexpr int MI = BM / 32, NJ = BN / 32;
  constexpr int STAGE_SH = (BM + BN) * 64;
  constexpr int CT_SH = (EPI == 0) ? BM * (BN + 8) : 2 * BM * (BN + 4);
  constexpr int SMEM_SH = STAGE_SH > CT_SH ? STAGE_SH : CT_SH;
  __shared__ __align__(16) short smem[SMEM_SH];
  short* Asd = smem;
  short* Bsd = smem + BM * 64;
  const int t = threadIdx.x;
  const int lane = t & 63;
  const int w = t >> 6;
  const int m0 = blockIdx.x * BM;
  const int n0 = blockIdx.y * BN;
  const int wm = (w >> 1) * (BM / 2);
  const int wn = (w & 1) * (BN / 2);
  f32x4 acc[MI][NJ] = {};
  const int l8 = lane >> 3;  // row within an 8-row wave-load
  const int sl = lane & 7;   // 16B slot within 128B row

  for (int k0 = 0; k0 < CC; k0 += 64) {
#pragma unroll
    for (int q = 0; q < BM / 32; ++q) {
      const int r = w * (BM / 4) + q * 8 + l8;
      const int cs = sl ^ (r & 7);
      gll16(A + (size_t)(m0 + r) * CC + k0 + cs * 8, Asd + (w * (BM / 4) + q * 8) * 64);
    }
#pragma unroll
    for (int q = 0; q < BN / 32; ++q) {
      const int r = w * (BN / 4) + q * 8 + l8;
      const int cs = sl ^ (r & 7);
      gll16(Bm + (size_t)(n0 + r) * CC + k0 + cs * 8, Bsd + (w * (BN / 4) + q * 8) * 64);
    }
    __syncthreads();  // drains vmcnt
    const int lr = lane & 15, g = lane >> 4;
#pragma unroll
    for (int kk = 0; kk < 2; ++kk) {
      bf16x8 af[MI], bf[NJ];
#pragma unroll
      for (int i = 0; i < MI; ++i) {
        const int row = wm + i * 16 + lr;
        af[i] = *(const bf16x8*)&Asd[row * 64 + ((kk * 4 + g) ^ (lr & 7)) * 8];
      }
#pragma unroll
      for (int j = 0; j < NJ; ++j) {
        const int row = wn + j * 16 + lr;
        bf[j] = *(const bf16x8*)&Bsd[row * 64 + ((kk * 4 + g) ^ (lr & 7)) * 8];
      }
#pragma unroll
      for (int i = 0; i < MI; ++i)
#pragma unroll
        for (int j = 0; j < NJ; ++j)
          acc[i][j] = __builtin_amdgcn_mfma_f32_16x16x32_bf16(af[i], bf[j], acc[i][j], 0, 0, 0);
    }
    __syncthreads();
  }

  const int lc = lane & 15, lr4 = (lane >> 4) * 4;
  if (EPI == 0) {
    // scatter C-frags to LDS bf16 tile, then coalesced 16B row stores
    unsigned short* O = (unsigned short*)out;
    unsigned short* Ct = (unsigned short*)smem;
#pragma unroll
    for (int i = 0; i < MI; ++i)
#pragma unroll
      for (int j = 0; j < NJ; ++j) {
        const float bb = bias[n0 + wn + j * 16 + lc];
#pragma unroll
        for (int r = 0; r < 4; ++r)
          Ct[(wm + i * 16 + lr4 + r) * (BN + 8) + wn + j * 16 + lc] = f2bf(acc[i][j][r] + bb);
      }
    __syncthreads();
#pragma unroll
    for (int rep = 0; rep < BM * BN / 8 / 256; ++rep) {
      const int c = rep * 256 + t;
      const int lrow = c / (BN / 8), lcol8 = (c % (BN / 8)) * 8;
      *(us8*)(O + (size_t)(m0 + lrow) * NO + n0 + lcol8) =
          *(const us8*)&Ct[lrow * (BN + 8) + lcol8];
    }
  } else {
    float* O = (float*)out;
    float* Cf = (float*)smem;
#pragma unroll
    for (int i = 0; i < MI; ++i)
#pragma unroll
      for (int j = 0; j < NJ; ++j) {
#pragma unroll
        for (int r = 0; r < 4; ++r) {
          const int lrow = wm + i * 16 + lr4 + r;
          Cf[lrow * (BN + 4) + wn + j * 16 + lc] = acc[i][j][r] + bias[m0 + lrow];
        }
      }
    __syncthreads();
#pragma unroll
    for (int rep = 0; rep < BM * BN / 4 / 256; ++rep) {
      const int c = rep * 256 + t;
      const int lrow = c / (BN / 4), lcol4 = (c % (BN / 4)) * 4;
      *(float4*)(O + (size_t)(m0 + lrow) * SD + n0 + lcol4) =
          *(const float4*)&Cf[lrow * (BN + 4) + lcol4];
    }
  }
}

// ---- MFMA neighborhood attention v3: one block per (8x8 query tile, head).
// 14x16 union (224 keys). No offs table (K-row offset is scalar per compile-time
// m; V addrs inline), no Pst LDS (PV A-fragment gathered via 8 shfl + 4 selects),
// single barrier (Vt). LDS = 14.8 KB.
__global__ __launch_bounds__(256) void nattn_mfma(const unsigned short* __restrict__ qkv,
                                                  unsigned short* __restrict__ att) {
  __shared__ short Vt[32][PROW];  // V^T: [d][key]
  const int t = threadIdx.x;
  const int lane = t & 63;
  const int w = t >> 6;
  const int g = lane >> 4;
  const int qcol = lane & 15;
  const int tile = blockIdx.x;
  const int h = blockIdx.y;
  const int ti = tile / 12, tj = tile % 12;
  const int qi0 = ti * 8, qj0 = tj * 8;
  const int ri0 = min(max(qi0, 3), 92) - 3;  // union row start
  const int cj0 = min(max(qj0, 3), 92) - 3;  // union col start

  // T14 issue-early: V gathers into registers, addresses computed inline
  us8 vreg[4];
  const int kg4 = t >> 2, d0 = (t & 3) * 8;
  if (t < 224) {
    const int vrow = min(ri0 + (kg4 >> 2), 95);
#pragma unroll
    for (int kk = 0; kk < 4; ++kk) {
      const int vcol = min(cj0 + min((kg4 & 3) * 4 + kk, 13), 95);
      vreg[kk] = *(const us8*)(qkv + (size_t)(vrow * HH + vcol) * NO + 2 * CC + h * DH + d0);
    }
  }

  // per-query window bitmasks (rows/cols of the 14x16 union)
  const int ql = w * 16 + qcol;
  const int qi = qi0 + (ql >> 3), qj = qj0 + (ql & 7);
  const int dr = min(max(qi, 3), 92) - 3 - ri0;  // in [0,7]
  const int dc = min(max(qj, 3), 92) - 3 - cj0;  // in [0,7]
  const unsigned rowmask = 0x7Fu << dr;
  const unsigned colm4 = (0x7Fu << dc) >> (4 * g);
  const bf16x8 qf = *(const bf16x8*)(qkv + (size_t)(qi * HH + qj) * NO + h * DH + g * 8);

  // QK^T: kf row offset is SCALAR per m (compile-time), col per-lane
  const int kcol = min(cj0 + min(qcol, 13), 95);
  const unsigned short* kbase = qkv + (size_t)kcol * NO + CC + h * DH + g * 8;
  f32x4 c[14];
#pragma unroll
  for (int m = 0; m < 14; ++m) {
    const int krow = min(ri0 + m, 95);
    const bf16x8 kf = *(const bf16x8*)(kbase + (size_t)krow * (HH * NO));
    c[m] = __builtin_amdgcn_mfma_f32_16x16x32_bf16(kf, qf, (f32x4){0.f, 0.f, 0.f, 0.f}, 0, 0, 0);
  }

  // mask + softmax: ru = m (compile-time), cu = 4g+r
  float mx = -1e30f;
#pragma unroll
  for (int m = 0; m < 14; ++m)
#pragma unroll
    for (int r = 0; r < 4; ++r) {
      const bool ok = ((rowmask >> m) & 1u) && ((colm4 >> r) & 1u);
      const float s = ok ? c[m][r] * 0.17677669529663687f : -1e30f;
      c[m][r] = s;
      mx = fmaxf(mx, s);
    }
  mx = fmaxf(mx, __shfl_xor(mx, 16));
  mx = fmaxf(mx, __shfl_xor(mx, 32));
  float sum = 0.f;
#pragma unroll
  for (int m = 0; m < 14; ++m)
#pragma unroll
    for (int r = 0; r < 4; ++r) { const float p = __expf(c[m][r] - mx); c[m][r] = p; sum += p; }
  sum += __shfl_xor(sum, 16);
  sum += __shfl_xor(sum, 32);
  const float inv = 1.0f / sum;

  // pack P to bf16 pairs in registers: pk[m][0]={keys 16m+4g+0,1}, [1]={+2,+3}
  unsigned pk[14][2];
#pragma unroll
  for (int m = 0; m < 14; ++m) {
    pk[m][0] = (unsigned)f2bf(c[m][0] * inv) | ((unsigned)f2bf(c[m][1] * inv) << 16);
    pk[m][1] = (unsigned)f2bf(c[m][2] * inv) | ((unsigned)f2bf(c[m][3] * inv) << 16);
  }

  // write-late: V register transpose -> Vt
  if (t < 224) {
#pragma unroll
    for (int jj = 0; jj < 8; ++jj) {
      ushort4 o;
      o.x = vreg[0][jj]; o.y = vreg[1][jj]; o.z = vreg[2][jj]; o.w = vreg[3][jj];
      *(ushort4*)&Vt[d0 + jj][kg4 * 4] = o;
    }
  }
  __syncthreads();  // Vt visible

  // PV: A-fragment for keys 8g..8g+7 of query qcol via cross-lane shfl.
  // srcA lane holds keys 16m'+4*((2g)&3)+0..3; srcB the next 4; m'=2tt+(g>>1).
  const int srcA = ((2 * g) & 3) * 16 + qcol;
  const int srcB = ((2 * g + 1) & 3) * 16 + qcol;
  const bool hi = (g >> 1) != 0;
  f32x4 o0 = {0.f, 0.f, 0.f, 0.f}, o1 = {0.f, 0.f, 0.f, 0.f};
#pragma unroll
  for (int tt = 0; tt < 7; ++tt) {
    const unsigned a0 = __shfl(pk[2 * tt][0], srcA);
    const unsigned a1 = __shfl(pk[2 * tt][1], srcA);
    const unsigned a2 = __shfl(pk[2 * tt][0], srcB);
    const unsigned a3 = __shfl(pk[2 * tt][1], srcB);
    const unsigned b0 = __shfl(pk[2 * tt + 1][0], srcA);
    const unsigned b1 = __shfl(pk[2 * tt + 1][1], srcA);
    const unsigned b2 = __shfl(pk[2 * tt + 1][0], srcB);
    const unsigned b3 = __shfl(pk[2 * tt + 1][1], srcB);
    union { unsigned u[4]; bf16x8 v; } pa;
    pa.u[0] = hi ? b0 : a0;
    pa.u[1] = hi ? b1 : a1;
    pa.u[2] = hi ? b2 : a2;
    pa.u[3] = hi ? b3 : a3;
    const bf16x8 v0 = *(const bf16x8*)&Vt[qcol][tt * 32 + g * 8];
    const bf16x8 v1 = *(const bf16x8*)&Vt[16 + qcol][tt * 32 + g * 8];
    o0 = __builtin_amdgcn_mfma_f32_16x16x32_bf16(pa.v, v0, o0, 0, 0, 0);
    o1 = __builtin_amdgcn_mfma_f32_16x16x32_bf16(pa.v, v1, o1, 0, 0, 0);
  }

  // epilogue: C layout col=lane&15, row=4g+r -> query w*16+4g+r, d = col
#pragma unroll
  for (int r = 0; r < 4; ++r) {
    const int qlr = w * 16 + g * 4 + r;
    const int s = (qi0 + (qlr >> 3)) * HH + qj0 + (qlr & 7);
    unsigned short* ap = att + (size_t)s * CC + h * DH;
    ap[qcol] = f2bf(o0[r]);
    ap[16 + qcol] = f2bf(o1[r]);
  }
}

extern "C" void kernel_launch(void* const* d_in, const int* in_sizes, int n_in,
                              void* d_out, int out_size, void* d_ws, size_t ws_size,
                              hipStream_t stream) {
  const float* x     = (const float*)d_in[0];
  const float* w_qkv = (const float*)d_in[1];
  const float* b_qkv = (const float*)d_in[2];
  const float* w_out = (const float*)d_in[3];
  const float* b_out = (const float*)d_in[4];
  float* out = (float*)d_out;

  unsigned short* ws   = (unsigned short*)d_ws;
  unsigned short* xbt  = ws;                         // [S][C]    bf16
  unsigned short* wqb  = xbt + (size_t)SD * CC;      // [768][256]
  unsigned short* wob  = wqb + (size_t)NO * CC;      // [256][256]
  unsigned short* qkvb = wob + (size_t)CC * CC;      // [S][768]
  unsigned short* attb = qkvb + (size_t)SD * NO;     // [S][256]

  prep<<<dim3(2304 + NWT / 4 / 256), dim3(256), 0, stream>>>(x, w_qkv, w_out, xbt, wqb);

  gemm_gll<64, 128, 0><<<dim3(SD / 64, NO / 128), dim3(256), 0, stream>>>(xbt, wqb, b_qkv, qkvb);

  nattn_mfma<<<dim3(144, NH), dim3(256), 0, stream>>>(qkvb, attb);

  gemm_gll<64, 128, 1><<<dim3(CC / 64, SD / 128), dim3(256), 0, stream>>>(wob, attb, b_out, out);
}

// Round 14
// 100.812 us; speedup vs baseline: 1.0242x; 1.0242x over previous
//
#include <hip/hip_runtime.h>
#include <hip/hip_bf16.h>
#include <math.h>

#define SD 9216   // S = H*W
#define HH 96     // H = W
#define CC 256    // C
#define NO 768    // 3*C
#define NH 8      // heads
#define DH 32     // head dim
#define NW1 (NO * CC)
#define NWT (NW1 + CC * CC)
#define PROW 232  // padded LDS row (shorts) for Vt

typedef short bf16x8 __attribute__((ext_vector_type(8)));
typedef short short8v __attribute__((ext_vector_type(8)));
typedef float f32x4 __attribute__((ext_vector_type(4)));
typedef unsigned short us8 __attribute__((ext_vector_type(8)));

__device__ __forceinline__ unsigned short f2bf(float f) {
  unsigned u = __float_as_uint(f);
  unsigned r = (u + 0x7FFF + ((u >> 16) & 1)) >> 16;  // RNE
  return (unsigned short)r;
}
// async global->LDS, 16B per lane; LDS dest is wave-uniform base + lane*16
__device__ __forceinline__ void gll16(const unsigned short* g, short* l) {
  __builtin_amdgcn_global_load_lds(
      (const __attribute__((address_space(1))) void*)g,
      (__attribute__((address_space(3))) void*)l, 16, 0, 0);
}

// ---- prep: transpose x [C][S] f32 -> xbt [S][C] bf16  AND  convert weights
__global__ __launch_bounds__(256) void prep(const float* __restrict__ x,
                                            const float* __restrict__ wq,
                                            const float* __restrict__ wo,
                                            unsigned short* __restrict__ xbt,
                                            unsigned short* __restrict__ wdst) {
  __shared__ float tile[32][33];
  const int b = blockIdx.x;
  const int t = threadIdx.x;
  if (b < 2304) {
    const int s0 = (b % 288) * 32;
    const int c0 = (b / 288) * 32;
    {
      const int c = t >> 3, s4 = (t & 7) * 4;
      const float4 v = *(const float4*)(x + (size_t)(c0 + c) * SD + s0 + s4);
      tile[c][s4] = v.x; tile[c][s4 + 1] = v.y; tile[c][s4 + 2] = v.z; tile[c][s4 + 3] = v.w;
    }
    __syncthreads();
    {
      const int s = t >> 3, c4 = (t & 7) * 4;
      ushort4 o;
      o.x = f2bf(tile[c4][s]);     o.y = f2bf(tile[c4 + 1][s]);
      o.z = f2bf(tile[c4 + 2][s]); o.w = f2bf(tile[c4 + 3][s]);
      *(ushort4*)(xbt + (size_t)(s0 + s) * CC + c0 + c4) = o;
    }
  } else {
    const int i = ((b - 2304) * 256 + t) * 4;
    if (i < NWT) {
      const float* src = (i < NW1) ? (wq + i) : (wo + (i - NW1));
      const float4 v = *(const float4*)src;
      ushort4 o;
      o.x = f2bf(v.x); o.y = f2bf(v.y); o.z = f2bf(v.z); o.w = f2bf(v.w);
      *(ushort4*)(wdst + i) = o;
    }
  }
}

// ---- bf16 MFMA GEMM, BMxBN tile, BK=64, 4 waves, K = CC = 256.
// global_load_lds staging, XOR chunk swizzle (both-sides). LDS-bounce epilogue:
// EPI 0: D[s][o] bf16 stride NO (qkv proj); EPI 1: D[o][s] f32 stride SD (out proj)
template <int BM, int BN, int EPI>
__global__ __launch_bounds__(256) void gemm_gll(const unsigned short* __restrict__ A,
                                                const unsigned short* __restrict__ Bm,
                                                const float* __restrict__ bias,
                                                void* __restrict__ out) {
  constexpr int MI = BM / 32, NJ = BN / 32;
  constexpr int STAGE_SH = (BM + BN) * 64;
  constexpr int CT_SH = (EPI == 0) ? BM * (BN + 8) : 2 * BM * (BN + 4);
  constexpr int SMEM_SH = STAGE_SH > CT_SH ? STAGE_SH : CT_SH;
  __shared__ __align__(16) short smem[SMEM_SH];
  short* Asd = smem;
  short* Bsd = smem + BM * 64;
  const int t = threadIdx.x;
  const int lane = t & 63;
  const int w = t >> 6;
  const int m0 = blockIdx.x * BM;
  const int n0 = blockIdx.y * BN;
  const int wm = (w >> 1) * (BM / 2);
  const int wn = (w & 1) * (BN / 2);
  f32x4 acc[MI][NJ] = {};
  const int l8 = lane >> 3;  // row within an 8-row wave-load
  const int sl = lane & 7;   // 16B slot within 128B row

  for (int k0 = 0; k0 < CC; k0 += 64) {
#pragma unroll
    for (int q = 0; q < BM / 32; ++q) {
      const int r = w * (BM / 4) + q * 8 + l8;
      const int cs = sl ^ (r & 7);
      gll16(A + (size_t)(m0 + r) * CC + k0 + cs * 8, Asd + (w * (BM / 4) + q * 8) * 64);
    }
#pragma unroll
    for (int q = 0; q < BN / 32; ++q) {
      const int r = w * (BN / 4) + q * 8 + l8;
      const int cs = sl ^ (r & 7);
      gll16(Bm + (size_t)(n0 + r) * CC + k0 + cs * 8, Bsd + (w * (BN / 4) + q * 8) * 64);
    }
    __syncthreads();  // drains vmcnt
    const int lr = lane & 15, g = lane >> 4;
#pragma unroll
    for (int kk = 0; kk < 2; ++kk) {
      bf16x8 af[MI], bf[NJ];
#pragma unroll
      for (int i = 0; i < MI; ++i) {
        const int row = wm + i * 16 + lr;
        af[i] = *(const bf16x8*)&Asd[row * 64 + ((kk * 4 + g) ^ (lr & 7)) * 8];
      }
#pragma unroll
      for (int j = 0; j < NJ; ++j) {
        const int row = wn + j * 16 + lr;
        bf[j] = *(const bf16x8*)&Bsd[row * 64 + ((kk * 4 + g) ^ (lr & 7)) * 8];
      }
#pragma unroll
      for (int i = 0; i < MI; ++i)
#pragma unroll
        for (int j = 0; j < NJ; ++j)
          acc[i][j] = __builtin_amdgcn_mfma_f32_16x16x32_bf16(af[i], bf[j], acc[i][j], 0, 0, 0);
    }
    __syncthreads();
  }

  const int lc = lane & 15, lr4 = (lane >> 4) * 4;
  if (EPI == 0) {
    // scatter C-frags to LDS bf16 tile, then coalesced 16B row stores
    unsigned short* O = (unsigned short*)out;
    unsigned short* Ct = (unsigned short*)smem;
#pragma unroll
    for (int i = 0; i < MI; ++i)
#pragma unroll
      for (int j = 0; j < NJ; ++j) {
        const float bb = bias[n0 + wn + j * 16 + lc];
#pragma unroll
        for (int r = 0; r < 4; ++r)
          Ct[(wm + i * 16 + lr4 + r) * (BN + 8) + wn + j * 16 + lc] = f2bf(acc[i][j][r] + bb);
      }
    __syncthreads();
#pragma unroll
    for (int rep = 0; rep < BM * BN / 8 / 256; ++rep) {
      const int c = rep * 256 + t;
      const int lrow = c / (BN / 8), lcol8 = (c % (BN / 8)) * 8;
      *(us8*)(O + (size_t)(m0 + lrow) * NO + n0 + lcol8) =
          *(const us8*)&Ct[lrow * (BN + 8) + lcol8];
    }
  } else {
    float* O = (float*)out;
    float* Cf = (float*)smem;
#pragma unroll
    for (int i = 0; i < MI; ++i)
#pragma unroll
      for (int j = 0; j < NJ; ++j) {
#pragma unroll
        for (int r = 0; r < 4; ++r) {
          const int lrow = wm + i * 16 + lr4 + r;
          Cf[lrow * (BN + 4) + wn + j * 16 + lc] = acc[i][j][r] + bias[m0 + lrow];
        }
      }
    __syncthreads();
#pragma unroll
    for (int rep = 0; rep < BM * BN / 4 / 256; ++rep) {
      const int c = rep * 256 + t;
      const int lrow = c / (BN / 4), lcol4 = (c % (BN / 4)) * 4;
      *(float4*)(O + (size_t)(m0 + lrow) * SD + n0 + lcol4) =
          *(const float4*)&Cf[lrow * (BN + 4) + lcol4];
    }
  }
}

// ---- MFMA neighborhood attention v2: one block per (8x8 query tile, head).
// Union flattened 14 rows x 16 cols = 224 keys: ru = key>>4 (= compile-time m in
// fragments), cu = key&15 -> window mask is two bitmask tests, no division.
// P stays in registers; PV streams 32-key slices through a 5 KB per-wave LDS
// buffer (intra-wave lgkmcnt, no barrier). LDS 21 KB.
__global__ __launch_bounds__(256) void nattn_mfma(const unsigned short* __restrict__ qkv,
                                                  unsigned short* __restrict__ att) {
  __shared__ int offs[224];            // key element-offset (row*NO) into qkv
  __shared__ short Vt[32][PROW];       // V^T: [d][key], 224 keys (2 masked cols)
  __shared__ unsigned Pst[4][16][20];  // per-wave P-slice staging (u32 = 2 bf16)
  const int t = threadIdx.x;
  const int lane = t & 63;
  const int w = t >> 6;
  const int g = lane >> 4;
  const int qcol = lane & 15;
  const int tile = blockIdx.x;
  const int h = blockIdx.y;
  const int ti = tile / 12, tj = tile % 12;
  const int qi0 = ti * 8, qj0 = tj * 8;
  const int ri0 = min(max(qi0, 3), 92) - 3;  // union row start
  const int cj0 = min(max(qj0, 3), 92) - 3;  // union col start

  if (t < 224) {
    const int ru = t >> 4, cu = min(t & 15, 13);  // cu 14,15 dup'd (always masked)
    offs[t] = (min(ri0 + ru, 95) * HH + min(cj0 + cu, 95)) * NO;
  }

  // per-query window bitmasks (rows/cols of the 14x16 union)
  const int ql = w * 16 + qcol;
  const int qi = qi0 + (ql >> 3), qj = qj0 + (ql & 7);
  const int dr = min(max(qi, 3), 92) - 3 - ri0;  // in [0,7]
  const int dc = min(max(qj, 3), 92) - 3 - cj0;  // in [0,7]
  const unsigned rowmask = 0x7Fu << dr;
  const unsigned colm4 = (0x7Fu << dc) >> (4 * g);
  const bf16x8 qf = *(const bf16x8*)(qkv + (size_t)(qi * HH + qj) * NO + h * DH + g * 8);
  __syncthreads();  // offs ready

  // T14 issue-early: V gathers into registers
  us8 vreg[4];
  const int kg4 = t >> 2, d0 = (t & 3) * 8;
  if (t < 224) {
#pragma unroll
    for (int kk = 0; kk < 4; ++kk)
      vreg[kk] = *(const us8*)(qkv + (size_t)offs[kg4 * 4 + kk] + 2 * CC + h * DH + d0);
  }

  // QK^T: A = K rows (via offs), B = Q rows; lane holds key 16m+4g+r, query qcol
  f32x4 c[14];
#pragma unroll
  for (int m = 0; m < 14; ++m) {
    const bf16x8 kf = *(const bf16x8*)(qkv + (size_t)offs[16 * m + qcol] + CC + h * DH + g * 8);
    c[m] = __builtin_amdgcn_mfma_f32_16x16x32_bf16(kf, qf, (f32x4){0.f, 0.f, 0.f, 0.f}, 0, 0, 0);
  }

  // mask + softmax: ru = m (compile-time), cu = 4g+r
  float mx = -1e30f;
#pragma unroll
  for (int m = 0; m < 14; ++m)
#pragma unroll
    for (int r = 0; r < 4; ++r) {
      const bool ok = ((rowmask >> m) & 1u) && ((colm4 >> r) & 1u);
      const float s = ok ? c[m][r] * 0.17677669529663687f : -1e30f;
      c[m][r] = s;
      mx = fmaxf(mx, s);
    }
  mx = fmaxf(mx, __shfl_xor(mx, 16));
  mx = fmaxf(mx, __shfl_xor(mx, 32));
  float sum = 0.f;
#pragma unroll
  for (int m = 0; m < 14; ++m)
#pragma unroll
    for (int r = 0; r < 4; ++r) { const float p = __expf(c[m][r] - mx); c[m][r] = p; sum += p; }
  sum += __shfl_xor(sum, 16);
  sum += __shfl_xor(sum, 32);
  const float inv = 1.0f / sum;

  // pack P to bf16 pairs in registers (keys 4g+2h, 4g+2h+1 of tile m)
  unsigned pk[14][2];
#pragma unroll
  for (int m = 0; m < 14; ++m) {
    pk[m][0] = (unsigned)f2bf(c[m][0] * inv) | ((unsigned)f2bf(c[m][1] * inv) << 16);
    pk[m][1] = (unsigned)f2bf(c[m][2] * inv) | ((unsigned)f2bf(c[m][3] * inv) << 16);
  }

  // write-late: V register transpose -> Vt
  if (t < 224) {
#pragma unroll
    for (int jj = 0; jj < 8; ++jj) {
      ushort4 o;
      o.x = vreg[0][jj]; o.y = vreg[1][jj]; o.z = vreg[2][jj]; o.w = vreg[3][jj];
      *(ushort4*)&Vt[d0 + jj][kg4 * 4] = o;
    }
  }
  __syncthreads();  // Vt visible

  // PV: per 32-key slice, stage own-wave P (lgkmcnt-ordered, no barrier), 2 MFMAs
  f32x4 o0 = {0.f, 0.f, 0.f, 0.f}, o1 = {0.f, 0.f, 0.f, 0.f};
#pragma unroll
  for (int tt = 0; tt < 7; ++tt) {
    *(uint2*)&Pst[w][qcol][2 * g] = make_uint2(pk[2 * tt][0], pk[2 * tt][1]);
    *(uint2*)&Pst[w][qcol][8 + 2 * g] = make_uint2(pk[2 * tt + 1][0], pk[2 * tt + 1][1]);
    const bf16x8 pa = *(const bf16x8*)&Pst[w][qcol][4 * g];  // keys 8g..8g+7, query qcol
    const bf16x8 v0 = *(const bf16x8*)&Vt[qcol][tt * 32 + g * 8];
    const bf16x8 v1 = *(const bf16x8*)&Vt[16 + qcol][tt * 32 + g * 8];
    o0 = __builtin_amdgcn_mfma_f32_16x16x32_bf16(pa, v0, o0, 0, 0, 0);
    o1 = __builtin_amdgcn_mfma_f32_16x16x32_bf16(pa, v1, o1, 0, 0, 0);
  }

  // epilogue: C layout col=lane&15, row=4g+r -> query w*16+4g+r, d = col
#pragma unroll
  for (int r = 0; r < 4; ++r) {
    const int qlr = w * 16 + g * 4 + r;
    const int s = (qi0 + (qlr >> 3)) * HH + qj0 + (qlr & 7);
    unsigned short* ap = att + (size_t)s * CC + h * DH;
    ap[qcol] = f2bf(o0[r]);
    ap[16 + qcol] = f2bf(o1[r]);
  }
}

extern "C" void kernel_launch(void* const* d_in, const int* in_sizes, int n_in,
                              void* d_out, int out_size, void* d_ws, size_t ws_size,
                              hipStream_t stream) {
  const float* x     = (const float*)d_in[0];
  const float* w_qkv = (const float*)d_in[1];
  const float* b_qkv = (const float*)d_in[2];
  const float* w_out = (const float*)d_in[3];
  const float* b_out = (const float*)d_in[4];
  float* out = (float*)d_out;

  unsigned short* ws   = (unsigned short*)d_ws;
  unsigned short* xbt  = ws;                         // [S][C]    bf16
  unsigned short* wqb  = xbt + (size_t)SD * CC;      // [768][256]
  unsigned short* wob  = wqb + (size_t)NO * CC;      // [256][256]
  unsigned short* qkvb = wob + (size_t)CC * CC;      // [S][768]
  unsigned short* attb = qkvb + (size_t)SD * NO;     // [S][256]

  prep<<<dim3(2304 + NWT / 4 / 256), dim3(256), 0, stream>>>(x, w_qkv, w_out, xbt, wqb);

  gemm_gll<64, 128, 0><<<dim3(SD / 64, NO / 128), dim3(256), 0, stream>>>(xbt, wqb, b_qkv, qkvb);

  nattn_mfma<<<dim3(144, NH), dim3(256), 0, stream>>>(qkvb, attb);

  gemm_gll<64, 128, 1><<<dim3(CC / 64, SD / 128), dim3(256), 0, stream>>>(wob, attb, b_out, out);
}